// Round 6
// baseline (601.444 us; speedup 1.0000x reference)
//
#include <hip/hip_runtime.h>
#include <math.h>

#define B_ 32
#define C_ 256
#define H_ 28
#define W_ 28
#define NPIX 784
#define HK 14
#define NKPIX 196
#define CM 1024
#define EPS_ 1e-5f
#define LN_INVN (1.0f / (C_ * NPIX))

typedef __attribute__((ext_vector_type(8))) short short8;
typedef __attribute__((ext_vector_type(4))) float float4_;

__device__ __forceinline__ float gelu_f(float x) {
    return 0.5f * x * (1.0f + erff(x * 0.70710678118654752f));
}
__device__ __forceinline__ short f2bf(float f) {
    union { float f; unsigned u; } x; x.f = f;
    unsigned r = x.u + 0x7FFF + ((x.u >> 16) & 1);
    return (short)(r >> 16);
}
__device__ __forceinline__ float bf2f(short s) {
    union { unsigned u; float f; } x; x.u = ((unsigned)(unsigned short)s) << 16;
    return x.f;
}

// ---- convert all 6 weight matrices to bf16 (layout [oc][k], k contiguous) ----
__global__ void wconv_kernel(const float* __restrict__ wq, const float* __restrict__ wk,
                             const float* __restrict__ wv, const float* __restrict__ wo,
                             const float* __restrict__ c1, const float* __restrict__ c2,
                             short* __restrict__ dst) {
    int idx = blockIdx.x * 256 + threadIdx.x;  // total 786432
    const float* src; int off;
    if (idx < 65536)       { src = wq; off = idx; }
    else if (idx < 131072) { src = wk; off = idx - 65536; }
    else if (idx < 196608) { src = wv; off = idx - 131072; }
    else if (idx < 262144) { src = wo; off = idx - 196608; }
    else if (idx < 524288) { src = c1; off = idx - 262144; }
    else                   { src = c2; off = idx - 524288; }
    dst[idx] = f2bf(src[off]);
}

// ---- prep for dwgelu: transpose dww to [tap][1024], fold dwb+BN2 to (sc,sh) ----
__global__ void dwprep_kernel(const float* __restrict__ dww, const float* __restrict__ dwb,
                              const float* __restrict__ g2, const float* __restrict__ b2,
                              const float* __restrict__ m2, const float* __restrict__ v2,
                              float* __restrict__ wt, float* __restrict__ sc2,
                              float* __restrict__ sh2) {
    int cm = blockIdx.x * 256 + threadIdx.x;  // 1024
    float sc = g2[cm] * rsqrtf(v2[cm] + EPS_);
    sc2[cm] = sc;
    sh2[cm] = (dwb[cm] - m2[cm]) * sc + b2[cm];
    #pragma unroll
    for (int tap = 0; tap < 9; ++tap) wt[tap * 1024 + cm] = dww[cm * 9 + tap];
}

// ---- generic LN stats reduce: 32 blocks, each folds cnt (sum,sumsq) pairs ----
__global__ void lnreduce_kernel(const float* __restrict__ part, int cnt,
                                float* __restrict__ out) {
    int b = blockIdx.x;
    const float* p = part + (long)b * cnt * 2;
    float s = 0.f, s2 = 0.f;
    for (int i = threadIdx.x; i < cnt; i += 256) {
        s += p[i * 2];
        s2 += p[i * 2 + 1];
    }
    #pragma unroll
    for (int o = 32; o > 0; o >>= 1) {
        s += __shfl_down(s, o);
        s2 += __shfl_down(s2, o);
    }
    __shared__ float ss[4][2];
    int wv = threadIdx.x >> 6;
    if ((threadIdx.x & 63) == 0) { ss[wv][0] = s; ss[wv][1] = s2; }
    __syncthreads();
    if (threadIdx.x == 0) {
        out[b * 2]     = ss[0][0] + ss[1][0] + ss[2][0] + ss[3][0];
        out[b * 2 + 1] = ss[0][1] + ss[1][1] + ss[2][1] + ss[3][1];
    }
}

// ---- LPU: depthwise 3x3 + bias + residual (fp32 channel-major), per-block LN1 partials ----
__global__ void lpu_kernel(const float* __restrict__ x, const float* __restrict__ w,
                           const float* __restrict__ bias, float* __restrict__ out,
                           float* __restrict__ part) {
    int idx = blockIdx.x * blockDim.x + threadIdx.x;
    int p = idx % NPIX;
    int c = (idx / NPIX) % C_;
    int y = p / W_, xx = p % W_;
    const float* xb = x + (size_t)(idx - p);
    const float* wc = w + c * 9;
    float acc = bias[c] + x[idx];
    #pragma unroll
    for (int dy = -1; dy <= 1; ++dy) {
        int yy = y + dy;
        if (yy < 0 || yy >= H_) continue;
        #pragma unroll
        for (int dx = -1; dx <= 1; ++dx) {
            int xc = xx + dx;
            if (xc < 0 || xc >= W_) continue;
            acc += wc[(dy + 1) * 3 + (dx + 1)] * xb[yy * W_ + xc];
        }
    }
    out[idx] = acc;
    float s = acc, s2 = acc * acc;
    #pragma unroll
    for (int o = 32; o > 0; o >>= 1) {
        s += __shfl_down(s, o);
        s2 += __shfl_down(s2, o);
    }
    __shared__ float ss[4][2];
    int wv = threadIdx.x >> 6;
    if ((threadIdx.x & 63) == 0) { ss[wv][0] = s; ss[wv][1] = s2; }
    __syncthreads();
    if (threadIdx.x == 0) {
        part[blockIdx.x * 2]     = ss[0][0] + ss[1][0] + ss[2][0] + ss[3][0];
        part[blockIdx.x * 2 + 1] = ss[0][1] + ss[1][1] + ss[2][1] + ss[3][1];
    }
}

// ---- transpose + LayerNorm: fp32 [b][256][784] -> bf16 [b][784][256] ----
__global__ void tln_kernel(const float* __restrict__ X, const float* __restrict__ st,
                           short* __restrict__ Y) {
    __shared__ float tile[32][33];
    int p0 = blockIdx.x * 32, c0 = blockIdx.y * 32, b = blockIdx.z;
    int tr = threadIdx.x >> 5, tc = threadIdx.x & 31;
    #pragma unroll
    for (int r = 0; r < 4; ++r) {
        int c = c0 + tr + r * 8, p = p0 + tc;
        tile[tr + r * 8][tc] = (p < NPIX) ? X[((long)b * C_ + c) * NPIX + p] : 0.f;
    }
    float sm = st[b * 2] * LN_INVN;
    float lr = rsqrtf(st[b * 2 + 1] * LN_INVN - sm * sm + EPS_);
    __syncthreads();
    #pragma unroll
    for (int r = 0; r < 4; ++r) {
        int p = p0 + tr + r * 8, c = c0 + tc;
        if (p < NPIX) Y[((long)b * NPIX + p) * C_ + c] = f2bf((tile[tc][tr + r * 8] - sm) * lr);
    }
}

// ---- kv depthwise 2x2 stride-2 (x1 fp32 channel-major -> bf16 pixel-major) ----
__global__ void kvconv_kernel(const float* __restrict__ x1, const float* __restrict__ w,
                              const float* __restrict__ bias, short* __restrict__ out) {
    int idx = blockIdx.x * 256 + threadIdx.x;
    if (idx >= B_ * NKPIX * C_) return;
    int c = idx & 255;
    int rest = idx >> 8;
    int p = rest % NKPIX;
    int b = rest / NKPIX;
    int yo = p / HK, xo = p % HK;
    const float* xb = x1 + ((long)b * C_ + c) * NPIX;
    const float* wc = w + c * 4;
    float a = bias[c]
            + wc[0] * xb[(2 * yo) * W_ + 2 * xo]     + wc[1] * xb[(2 * yo) * W_ + 2 * xo + 1]
            + wc[2] * xb[(2 * yo + 1) * W_ + 2 * xo] + wc[3] * xb[(2 * yo + 1) * W_ + 2 * xo + 1];
    out[idx] = f2bf(a);
}

// ---- MFMA GEMM: D[b][p][oc] = sum_k Act[b][p][k] * Wb[oc][k]  (bf16 in, fp32 acc) ----
template <int EPI>
__global__ __launch_bounds__(256) void mfma_gemm(
    const short* __restrict__ Act, const short* __restrict__ Wb,
    int M, int N, int K,
    const float* __restrict__ bias,
    const float* __restrict__ g, const float* __restrict__ bb,
    const float* __restrict__ mm, const float* __restrict__ vv,
    const float* __restrict__ res, float* __restrict__ opart,
    short* __restrict__ outh, float* __restrict__ outf) {
    __shared__ short As[128 * 40];
    __shared__ short Bs[128 * 40];
    const int t = threadIdx.x;
    const int m0 = blockIdx.x * 128;
    const int n0 = blockIdx.y * 128;
    const int b = blockIdx.z;
    const int w = t >> 6, lane = t & 63;
    const int wm = (w & 1) * 64, wn = (w >> 1) * 64;
    const int col = lane & 15, quad = lane >> 4;
    const short* Ab = Act + (long)b * M * K;

    float4_ acc[4][4];
    #pragma unroll
    for (int i = 0; i < 4; ++i)
        #pragma unroll
        for (int j = 0; j < 4; ++j)
            acc[i][j] = (float4_){0.f, 0.f, 0.f, 0.f};

    const int arow = t >> 2, aseg = t & 3;
    for (int k0 = 0; k0 < K; k0 += 32) {
        __syncthreads();
        #pragma unroll
        for (int hh = 0; hh < 2; ++hh) {
            int row = arow + hh * 64;
            int gm = m0 + row;
            float4 av = make_float4(0.f, 0.f, 0.f, 0.f);
            if (gm < M) av = *(const float4*)(Ab + (long)gm * K + k0 + aseg * 8);
            *(float4*)(As + row * 40 + aseg * 8) = av;
            float4 bv = *(const float4*)(Wb + (long)(n0 + row) * K + k0 + aseg * 8);
            *(float4*)(Bs + row * 40 + aseg * 8) = bv;
        }
        __syncthreads();
        short8 af[4], bf[4];
        #pragma unroll
        for (int i = 0; i < 4; ++i)
            af[i] = *(const short8*)(As + (wm + i * 16 + col) * 40 + quad * 8);
        #pragma unroll
        for (int j = 0; j < 4; ++j)
            bf[j] = *(const short8*)(Bs + (wn + j * 16 + col) * 40 + quad * 8);
        #pragma unroll
        for (int i = 0; i < 4; ++i)
            #pragma unroll
            for (int j = 0; j < 4; ++j)
                acc[i][j] = __builtin_amdgcn_mfma_f32_16x16x32_bf16(af[i], bf[j], acc[i][j], 0, 0, 0);
    }

    float s1 = 0.f, s2s = 0.f;
    #pragma unroll
    for (int i = 0; i < 4; ++i) {
        int pbase = m0 + wm + i * 16 + quad * 4;
        #pragma unroll
        for (int j = 0; j < 4; ++j) {
            int oc = n0 + wn + j * 16 + col;
            if (EPI == 0) {
                float cb = bias[oc];
                #pragma unroll
                for (int r = 0; r < 4; ++r) {
                    int p = pbase + r;
                    if (p < M) outh[((long)b * M + p) * N + oc] = f2bf(acc[i][j][r] + cb);
                }
            } else if (EPI == 1) {
                float sc = g[oc] * rsqrtf(vv[oc] + EPS_);
                float sh = bb[oc] - mm[oc] * sc;
                float cb = bias[oc];
                #pragma unroll
                for (int r = 0; r < 4; ++r) {
                    int p = pbase + r;
                    if (p < M) outh[((long)b * M + p) * N + oc] =
                        f2bf(gelu_f((acc[i][j][r] + cb) * sc + sh));
                }
            } else if (EPI == 2) {
                float cb = bias[oc];
                if (pbase < M) {
                    #pragma unroll
                    for (int r = 0; r < 4; ++r) {
                        long jj = ((long)b * M + pbase + r) * 256 + oc;
                        float val = acc[i][j][r] + cb + res[jj];
                        outf[jj] = val;
                        s1 += val; s2s += val * val;
                    }
                }
            } else {
                float sc = g[oc] * rsqrtf(vv[oc] + EPS_);
                float sh = bb[oc] - mm[oc] * sc;
                float cb = bias[oc];
                if (pbase < M) {
                    long base = ((long)b * N + oc) * M + pbase;
                    float4 rv = *(const float4*)(res + base);
                    float4 y;
                    y.x = (acc[i][j][0] + cb) * sc + sh + rv.x;
                    y.y = (acc[i][j][1] + cb) * sc + sh + rv.y;
                    y.z = (acc[i][j][2] + cb) * sc + sh + rv.z;
                    y.w = (acc[i][j][3] + cb) * sc + sh + rv.w;
                    *(float4*)(outf + base) = y;
                }
            }
        }
    }
    if (EPI == 2) {
        #pragma unroll
        for (int o = 32; o > 0; o >>= 1) {
            s1 += __shfl_down(s1, o);
            s2s += __shfl_down(s2s, o);
        }
        if (lane == 0) {
            long slot = (((long)blockIdx.z * gridDim.y + blockIdx.y) * gridDim.x + blockIdx.x) * 4 + w;
            opart[slot * 2]     = s1;
            opart[slot * 2 + 1] = s2s;
        }
    }
}

// ---- MFMA flash attention: block = (128-query tile, head, batch) ----
// q/k/v bf16 pixel-major [b][p][256]; pos fp32 [8][784][196]; out bf16 [b][p][256]
// No max-subtraction (scores bounded by construction) -> chunked softmax is
// purely additive: O = sum_chunks P_chunk @ V_chunk, l = sum exp.
__global__ __launch_bounds__(256) void attn_kernel(const short* __restrict__ q,
                                                   const short* __restrict__ k,
                                                   const short* __restrict__ v,
                                                   const float* __restrict__ pos_b,
                                                   short* __restrict__ out) {
    __shared__ short Qs[128 * 40];   // [query][d], pad 40
    __shared__ short Ks[224 * 40];   // [key][d], rows 196.. zero
    __shared__ short Vt[32 * 240];   // [d][key], cols 196.. zero
    __shared__ short Ps[128 * 136];  // [query][local key 0..127], cols 112.. zero
    const int qt0 = blockIdx.x * 128;
    const int h = blockIdx.y;
    const int b = blockIdx.z;
    const int t = threadIdx.x;
    const short8 z8 = {0, 0, 0, 0, 0, 0, 0, 0};
    // stage Q (512 x 16B)
    for (int e = t; e < 512; e += 256) {
        int row = e >> 2, seg = e & 3;
        int gq = qt0 + row;
        short8 v8 = (gq < NPIX)
            ? *(const short8*)(q + ((long)(b * NPIX + gq)) * 256 + h * 32 + seg * 8) : z8;
        *(short8*)(Qs + row * 40 + seg * 8) = v8;
    }
    // stage K (896 x 16B)
    for (int e = t; e < 896; e += 256) {
        int row = e >> 2, seg = e & 3;
        short8 v8 = (row < NKPIX)
            ? *(const short8*)(k + ((long)(b * NKPIX + row)) * 256 + h * 32 + seg * 8) : z8;
        *(short8*)(Ks + row * 40 + seg * 8) = v8;
    }
    // stage V transposed (7680 elems)
    for (int e = t; e < 7680; e += 256) {
        int key = e >> 5, d = e & 31;
        Vt[d * 240 + key] = (key < NKPIX)
            ? v[((long)(b * NKPIX + key)) * 256 + h * 32 + d] : (short)0;
    }
    // zero Ps pad cols 112..135
    for (int e = t; e < 128 * 24; e += 256) {
        Ps[(e / 24) * 136 + 112 + (e % 24)] = 0;
    }
    __syncthreads();

    const int w = t >> 6, lane = t & 63;
    const int col = lane & 15, quad = lane >> 4;
    const float scale = 0.17677669529663689f;
    const float4_ z4 = {0.f, 0.f, 0.f, 0.f};
    short8 afq[2];
    #pragma unroll
    for (int i = 0; i < 2; ++i)
        afq[i] = *(const short8*)(Qs + (w * 32 + i * 16 + col) * 40 + quad * 8);

    float4_ accO[2][2];
    #pragma unroll
    for (int i = 0; i < 2; ++i)
        #pragma unroll
        for (int nt = 0; nt < 2; ++nt) accO[i][nt] = z4;
    float lsum[2][4];
    #pragma unroll
    for (int i = 0; i < 2; ++i)
        #pragma unroll
        for (int r = 0; r < 4; ++r) lsum[i][r] = 0.f;

    for (int kc = 0; kc < 2; ++kc) {
        // S = Q K^T (one mfma per tile), + pos, exp, write P to LDS (A-layout rows owned by this wave)
        #pragma unroll
        for (int i = 0; i < 2; ++i) {
            int qbase = qt0 + w * 32 + i * 16 + quad * 4;
            #pragma unroll
            for (int nt = 0; nt < 7; ++nt) {
                int key = kc * 112 + nt * 16 + col;
                short8 bfk = *(const short8*)(Ks + key * 40 + quad * 8);
                float4_ s4 = __builtin_amdgcn_mfma_f32_16x16x32_bf16(afq[i], bfk, z4, 0, 0, 0);
                bool kvalid = key < NKPIX;
                #pragma unroll
                for (int r = 0; r < 4; ++r) {
                    int qq = qbase + r;
                    float pos = (kvalid && qq < NPIX)
                        ? pos_b[((long)h * NPIX + qq) * NKPIX + key] : 0.f;
                    float p = kvalid ? __expf(s4[r] * scale + pos) : 0.f;
                    lsum[i][r] += p;
                    Ps[(w * 32 + i * 16 + quad * 4 + r) * 136 + nt * 16 + col] = f2bf(p);
                }
            }
        }
        // O += P V (same-wave LDS dependency only; lgkmcnt handles ordering)
        #pragma unroll
        for (int ks = 0; ks < 4; ++ks) {
            #pragma unroll
            for (int i = 0; i < 2; ++i) {
                short8 afp = *(const short8*)(Ps + (w * 32 + i * 16 + col) * 136 + ks * 32 + quad * 8);
                #pragma unroll
                for (int nt = 0; nt < 2; ++nt) {
                    short8 bfv = *(const short8*)(Vt + (nt * 16 + col) * 240 + kc * 112 + ks * 32 + quad * 8);
                    accO[i][nt] = __builtin_amdgcn_mfma_f32_16x16x32_bf16(afp, bfv, accO[i][nt], 0, 0, 0);
                }
            }
        }
    }
    // reduce row sums across the 16-lane col group
    #pragma unroll
    for (int i = 0; i < 2; ++i)
        #pragma unroll
        for (int r = 0; r < 4; ++r) {
            float s = lsum[i][r];
            s += __shfl_xor(s, 1);
            s += __shfl_xor(s, 2);
            s += __shfl_xor(s, 4);
            s += __shfl_xor(s, 8);
            lsum[i][r] = 1.f / s;
        }
    // write O / l
    #pragma unroll
    for (int i = 0; i < 2; ++i) {
        int qbase = qt0 + w * 32 + i * 16 + quad * 4;
        #pragma unroll
        for (int nt = 0; nt < 2; ++nt) {
            #pragma unroll
            for (int r = 0; r < 4; ++r) {
                int qq = qbase + r;
                if (qq < NPIX)
                    out[((long)(b * NPIX + qq)) * 256 + h * 32 + nt * 16 + col] =
                        f2bf(accO[i][nt][r] * lsum[i][r]);
            }
        }
    }
}

// ---- dwconv3x3 + BN2 + GELU, 8 channels/thread via short8 ----
__global__ __launch_bounds__(256) void dwgelu_kernel(
    const short* __restrict__ t2, const float* __restrict__ wt,
    const float* __restrict__ sc2, const float* __restrict__ sh2,
    short* __restrict__ t3) {
    int idx = blockIdx.x * 256 + threadIdx.x;  // B*NPIX*128 = 3,211,264
    int cm8 = idx & 127;
    int rest = idx >> 7;
    int p = rest % NPIX;
    int b = rest / NPIX;
    int py = p / W_, px = p % W_;
    int cm0 = cm8 * 8;
    const short* tb = t2 + ((long)b * NPIX) * CM + cm0;
    float acc[8];
    #pragma unroll
    for (int r = 0; r < 8; ++r) acc[r] = 0.f;
    #pragma unroll
    for (int dy = -1; dy <= 1; ++dy) {
        int yy = py + dy;
        if (yy < 0 || yy >= H_) continue;
        #pragma unroll
        for (int dx = -1; dx <= 1; ++dx) {
            int xc = px + dx;
            if (xc < 0 || xc >= W_) continue;
            int tap = (dy + 1) * 3 + (dx + 1);
            short8 tv = *(const short8*)(tb + (long)(yy * W_ + xc) * CM);
            float4 w0 = *(const float4*)(wt + tap * 1024 + cm0);
            float4 w1 = *(const float4*)(wt + tap * 1024 + cm0 + 4);
            acc[0] += bf2f(tv[0]) * w0.x;
            acc[1] += bf2f(tv[1]) * w0.y;
            acc[2] += bf2f(tv[2]) * w0.z;
            acc[3] += bf2f(tv[3]) * w0.w;
            acc[4] += bf2f(tv[4]) * w1.x;
            acc[5] += bf2f(tv[5]) * w1.y;
            acc[6] += bf2f(tv[6]) * w1.z;
            acc[7] += bf2f(tv[7]) * w1.w;
        }
    }
    float4 sa = *(const float4*)(sc2 + cm0);
    float4 sb = *(const float4*)(sc2 + cm0 + 4);
    float4 ha = *(const float4*)(sh2 + cm0);
    float4 hb = *(const float4*)(sh2 + cm0 + 4);
    short8 ov;
    ov[0] = f2bf(gelu_f(acc[0] * sa.x + ha.x));
    ov[1] = f2bf(gelu_f(acc[1] * sa.y + ha.y));
    ov[2] = f2bf(gelu_f(acc[2] * sa.z + ha.z));
    ov[3] = f2bf(gelu_f(acc[3] * sa.w + ha.w));
    ov[4] = f2bf(gelu_f(acc[4] * sb.x + hb.x));
    ov[5] = f2bf(gelu_f(acc[5] * sb.y + hb.y));
    ov[6] = f2bf(gelu_f(acc[6] * sb.z + hb.z));
    ov[7] = f2bf(gelu_f(acc[7] * sb.w + hb.w));
    *(short8*)(t3 + ((long)b * NPIX + p) * CM + cm0) = ov;
}

extern "C" void kernel_launch(void* const* d_in, const int* in_sizes, int n_in,
                              void* d_out, int out_size, void* d_ws, size_t ws_size,
                              hipStream_t stream) {
    const float* x     = (const float*)d_in[0];
    const float* lpu_w = (const float*)d_in[1];
    const float* lpu_b = (const float*)d_in[2];
    const float* dw_w  = (const float*)d_in[3];
    const float* dw_b  = (const float*)d_in[4];
    const float* wq    = (const float*)d_in[5];
    const float* bq    = (const float*)d_in[6];
    const float* wk    = (const float*)d_in[7];
    const float* bk    = (const float*)d_in[8];
    const float* wv    = (const float*)d_in[9];
    const float* bv    = (const float*)d_in[10];
    const float* wo    = (const float*)d_in[11];
    const float* bo    = (const float*)d_in[12];
    const float* posb  = (const float*)d_in[13];
    const float* c1_w  = (const float*)d_in[14];
    const float* c1_b  = (const float*)d_in[15];
    const float* bn1_g = (const float*)d_in[16];
    const float* bn1_b = (const float*)d_in[17];
    const float* bn1_m = (const float*)d_in[18];
    const float* bn1_v = (const float*)d_in[19];
    const float* dw2_w = (const float*)d_in[20];
    const float* dw2_b = (const float*)d_in[21];
    const float* bn2_g = (const float*)d_in[22];
    const float* bn2_b = (const float*)d_in[23];
    const float* bn2_m = (const float*)d_in[24];
    const float* bn2_v = (const float*)d_in[25];
    const float* c2_w  = (const float*)d_in[26];
    const float* c2_b  = (const float*)d_in[27];
    const float* bn3_g = (const float*)d_in[28];
    const float* bn3_b = (const float*)d_in[29];
    const float* bn3_m = (const float*)d_in[30];
    const float* bn3_v = (const float*)d_in[31];

    const long n1  = (long)B_ * C_ * NPIX;    // 6,422,528
    const long nkv = (long)B_ * C_ * NKPIX;   // 1,605,632
    const long nm  = (long)B_ * CM * NPIX;    // 25,690,112
    const int  nblk1 = (int)(n1 / 256);       // 25088 lpu blocks (784 per sample)

    char* base = (char*)d_ws;
    float* x1   = (float*)base; base += n1 * 4;
    float* x2c  = (float*)base; base += n1 * 4;
    short* x1n  = (short*)base; base += n1 * 2;
    short* qb   = (short*)base; base += n1 * 2;
    short* tmpb = (short*)base; base += n1 * 2;
    short* t1n  = (short*)base; base += n1 * 2;
    short* kvb  = (short*)base; base += nkv * 2;
    short* kb   = (short*)base; base += nkv * 2;
    short* vb   = (short*)base; base += nkv * 2;
    short* t2   = (short*)base; base += nm * 2;
    short* t3   = (short*)base; base += nm * 2;
    short* wbf  = (short*)base; base += 786432L * 2;
    float* stats = (float*)base; base += 128 * 4;
    float* dwt   = (float*)base; base += 9216 * 4;   // [9][1024]
    float* dsc   = (float*)base; base += 1024 * 4;
    float* dsh   = (float*)base; base += 1024 * 4;
    float* part1 = (float*)base; base += (long)nblk1 * 2 * 4;
    float* part2 = (float*)base;
    float* outp = (float*)d_out;

    wconv_kernel<<<3072, 256, 0, stream>>>(wq, wk, wv, wo, c1_w, c2_w, wbf);
    dwprep_kernel<<<4, 256, 0, stream>>>(dw2_w, dw2_b, bn2_g, bn2_b, bn2_m, bn2_v,
                                         dwt, dsc, dsh);
    lpu_kernel<<<nblk1, 256, 0, stream>>>(x, lpu_w, lpu_b, x1, part1);
    lnreduce_kernel<<<B_, 256, 0, stream>>>(part1, nblk1 / B_, stats);
    kvconv_kernel<<<(int)((nkv + 255) / 256), 256, 0, stream>>>(x1, dw_w, dw_b, kvb);
    tln_kernel<<<dim3(25, 8, B_), 256, 0, stream>>>(x1, stats, x1n);
    // q/k/v projections
    mfma_gemm<0><<<dim3(7, 2, B_), 256, 0, stream>>>(
        x1n, wbf, NPIX, 256, 256, bq, nullptr, nullptr, nullptr, nullptr,
        nullptr, nullptr, qb, nullptr);
    mfma_gemm<0><<<dim3(2, 2, B_), 256, 0, stream>>>(
        kvb, wbf + 65536, NKPIX, 256, 256, bk, nullptr, nullptr, nullptr, nullptr,
        nullptr, nullptr, kb, nullptr);
    mfma_gemm<0><<<dim3(2, 2, B_), 256, 0, stream>>>(
        kvb, wbf + 131072, NKPIX, 256, 256, bv, nullptr, nullptr, nullptr, nullptr,
        nullptr, nullptr, vb, nullptr);
    attn_kernel<<<dim3(7, 8, B_), 256, 0, stream>>>(qb, kb, vb, posb, tmpb);
    // wo + flat residual + per-wave LN2 partials (grid 7x2x32 -> 56 slots per b)
    mfma_gemm<2><<<dim3(7, 2, B_), 256, 0, stream>>>(
        tmpb, wbf + 196608, NPIX, 256, 256, bo, nullptr, nullptr, nullptr, nullptr,
        x1, part2, nullptr, x2c);
    lnreduce_kernel<<<B_, 256, 0, stream>>>(part2, 56, stats + 64);
    tln_kernel<<<dim3(25, 8, B_), 256, 0, stream>>>(x2c, stats + 64, t1n);
    // conv1 1x1 + BN1 + GELU
    mfma_gemm<1><<<dim3(7, 8, B_), 256, 0, stream>>>(
        t1n, wbf + 262144, NPIX, CM, 256, c1_b, bn1_g, bn1_b, bn1_m, bn1_v,
        nullptr, nullptr, t2, nullptr);
    dwgelu_kernel<<<(int)(B_ * NPIX * 128 / 256), 256, 0, stream>>>(t2, dwt, dsc, dsh, t3);
    // conv2 1x1 + BN3 + residual -> d_out (channel-major)
    mfma_gemm<3><<<dim3(7, 2, B_), 256, 0, stream>>>(
        t3, wbf + 524288, NPIX, 256, CM, c2_b, bn3_g, bn3_b, bn3_m, bn3_v,
        x2c, nullptr, nullptr, outp);
}

// Round 7
// 521.019 us; speedup vs baseline: 1.1544x; 1.1544x over previous
//
#include <hip/hip_runtime.h>
#include <math.h>

#define B_ 32
#define C_ 256
#define H_ 28
#define W_ 28
#define NPIX 784
#define HK 14
#define NKPIX 196
#define CM 1024
#define EPS_ 1e-5f
#define LN_INVN (1.0f / (C_ * NPIX))

typedef __attribute__((ext_vector_type(8))) short short8;
typedef __attribute__((ext_vector_type(4))) short short4_;
typedef __attribute__((ext_vector_type(4))) float float4_;

__device__ __forceinline__ float gelu_f(float x) {
    return 0.5f * x * (1.0f + erff(x * 0.70710678118654752f));
}
__device__ __forceinline__ short f2bf(float f) {
    union { float f; unsigned u; } x; x.f = f;
    unsigned r = x.u + 0x7FFF + ((x.u >> 16) & 1);
    return (short)(r >> 16);
}
__device__ __forceinline__ float bf2f(short s) {
    union { unsigned u; float f; } x; x.u = ((unsigned)(unsigned short)s) << 16;
    return x.f;
}

// ---- convert all 6 weight matrices to bf16 (layout [oc][k], k contiguous) ----
__global__ void wconv_kernel(const float* __restrict__ wq, const float* __restrict__ wk,
                             const float* __restrict__ wv, const float* __restrict__ wo,
                             const float* __restrict__ c1, const float* __restrict__ c2,
                             short* __restrict__ dst) {
    int idx = blockIdx.x * 256 + threadIdx.x;  // total 786432
    const float* src; int off;
    if (idx < 65536)       { src = wq; off = idx; }
    else if (idx < 131072) { src = wk; off = idx - 65536; }
    else if (idx < 196608) { src = wv; off = idx - 131072; }
    else if (idx < 262144) { src = wo; off = idx - 196608; }
    else if (idx < 524288) { src = c1; off = idx - 262144; }
    else                   { src = c2; off = idx - 524288; }
    dst[idx] = f2bf(src[off]);
}

// ---- prep for dwgelu: transpose dww to [tap][1024], fold dwb+BN2 to (sc,sh) ----
__global__ void dwprep_kernel(const float* __restrict__ dww, const float* __restrict__ dwb,
                              const float* __restrict__ g2, const float* __restrict__ b2,
                              const float* __restrict__ m2, const float* __restrict__ v2,
                              float* __restrict__ wt, float* __restrict__ sc2,
                              float* __restrict__ sh2) {
    int cm = blockIdx.x * 256 + threadIdx.x;  // 1024
    float sc = g2[cm] * rsqrtf(v2[cm] + EPS_);
    sc2[cm] = sc;
    sh2[cm] = (dwb[cm] - m2[cm]) * sc + b2[cm];
    #pragma unroll
    for (int tap = 0; tap < 9; ++tap) wt[tap * 1024 + cm] = dww[cm * 9 + tap];
}

// ---- generic LN stats reduce: 32 blocks, each folds cnt (sum,sumsq) pairs ----
__global__ void lnreduce_kernel(const float* __restrict__ part, int cnt,
                                float* __restrict__ out) {
    int b = blockIdx.x;
    const float* p = part + (long)b * cnt * 2;
    float s = 0.f, s2 = 0.f;
    for (int i = threadIdx.x; i < cnt; i += 256) {
        s += p[i * 2];
        s2 += p[i * 2 + 1];
    }
    #pragma unroll
    for (int o = 32; o > 0; o >>= 1) {
        s += __shfl_down(s, o);
        s2 += __shfl_down(s2, o);
    }
    __shared__ float ss[4][2];
    int wv = threadIdx.x >> 6;
    if ((threadIdx.x & 63) == 0) { ss[wv][0] = s; ss[wv][1] = s2; }
    __syncthreads();
    if (threadIdx.x == 0) {
        out[b * 2]     = ss[0][0] + ss[1][0] + ss[2][0] + ss[3][0];
        out[b * 2 + 1] = ss[0][1] + ss[1][1] + ss[2][1] + ss[3][1];
    }
}

// ---- LPU: depthwise 3x3 + bias + residual (fp32 channel-major), per-block LN1 partials ----
__global__ void lpu_kernel(const float* __restrict__ x, const float* __restrict__ w,
                           const float* __restrict__ bias, float* __restrict__ out,
                           float* __restrict__ part) {
    int idx = blockIdx.x * blockDim.x + threadIdx.x;
    int p = idx % NPIX;
    int c = (idx / NPIX) % C_;
    int y = p / W_, xx = p % W_;
    const float* xb = x + (size_t)(idx - p);
    const float* wc = w + c * 9;
    float acc = bias[c] + x[idx];
    #pragma unroll
    for (int dy = -1; dy <= 1; ++dy) {
        int yy = y + dy;
        if (yy < 0 || yy >= H_) continue;
        #pragma unroll
        for (int dx = -1; dx <= 1; ++dx) {
            int xc = xx + dx;
            if (xc < 0 || xc >= W_) continue;
            acc += wc[(dy + 1) * 3 + (dx + 1)] * xb[yy * W_ + xc];
        }
    }
    out[idx] = acc;
    float s = acc, s2 = acc * acc;
    #pragma unroll
    for (int o = 32; o > 0; o >>= 1) {
        s += __shfl_down(s, o);
        s2 += __shfl_down(s2, o);
    }
    __shared__ float ss[4][2];
    int wv = threadIdx.x >> 6;
    if ((threadIdx.x & 63) == 0) { ss[wv][0] = s; ss[wv][1] = s2; }
    __syncthreads();
    if (threadIdx.x == 0) {
        part[blockIdx.x * 2]     = ss[0][0] + ss[1][0] + ss[2][0] + ss[3][0];
        part[blockIdx.x * 2 + 1] = ss[0][1] + ss[1][1] + ss[2][1] + ss[3][1];
    }
}

// ---- transpose + LayerNorm: fp32 [b][256][784] -> bf16 [b][784][256] ----
__global__ void tln_kernel(const float* __restrict__ X, const float* __restrict__ st,
                           short* __restrict__ Y) {
    __shared__ float tile[32][33];
    int p0 = blockIdx.x * 32, c0 = blockIdx.y * 32, b = blockIdx.z;
    int tr = threadIdx.x >> 5, tc = threadIdx.x & 31;
    #pragma unroll
    for (int r = 0; r < 4; ++r) {
        int c = c0 + tr + r * 8, p = p0 + tc;
        tile[tr + r * 8][tc] = (p < NPIX) ? X[((long)b * C_ + c) * NPIX + p] : 0.f;
    }
    float sm = st[b * 2] * LN_INVN;
    float lr = rsqrtf(st[b * 2 + 1] * LN_INVN - sm * sm + EPS_);
    __syncthreads();
    #pragma unroll
    for (int r = 0; r < 4; ++r) {
        int p = p0 + tr + r * 8, c = c0 + tc;
        if (p < NPIX) Y[((long)b * NPIX + p) * C_ + c] = f2bf((tile[tc][tr + r * 8] - sm) * lr);
    }
}

// ---- kv depthwise 2x2 stride-2 (x1 fp32 channel-major -> bf16 pixel-major) ----
__global__ void kvconv_kernel(const float* __restrict__ x1, const float* __restrict__ w,
                              const float* __restrict__ bias, short* __restrict__ out) {
    int idx = blockIdx.x * 256 + threadIdx.x;
    if (idx >= B_ * NKPIX * C_) return;
    int c = idx & 255;
    int rest = idx >> 8;
    int p = rest % NKPIX;
    int b = rest / NKPIX;
    int yo = p / HK, xo = p % HK;
    const float* xb = x1 + ((long)b * C_ + c) * NPIX;
    const float* wc = w + c * 4;
    float a = bias[c]
            + wc[0] * xb[(2 * yo) * W_ + 2 * xo]     + wc[1] * xb[(2 * yo) * W_ + 2 * xo + 1]
            + wc[2] * xb[(2 * yo + 1) * W_ + 2 * xo] + wc[3] * xb[(2 * yo + 1) * W_ + 2 * xo + 1];
    out[idx] = f2bf(a);
}

// ---- MFMA GEMM: D[b][p][oc] = sum_k Act[b][p][k] * Wb[oc][k]  (bf16 in, fp32 acc) ----
template <int EPI>
__global__ __launch_bounds__(256) void mfma_gemm(
    const short* __restrict__ Act, const short* __restrict__ Wb,
    int M, int N, int K,
    const float* __restrict__ bias,
    const float* __restrict__ g, const float* __restrict__ bb,
    const float* __restrict__ mm, const float* __restrict__ vv,
    const float* __restrict__ res, float* __restrict__ opart,
    short* __restrict__ outh, float* __restrict__ outf) {
    __shared__ short As[128 * 40];
    __shared__ short Bs[128 * 40];
    const int t = threadIdx.x;
    const int m0 = blockIdx.x * 128;
    const int n0 = blockIdx.y * 128;
    const int b = blockIdx.z;
    const int w = t >> 6, lane = t & 63;
    const int wm = (w & 1) * 64, wn = (w >> 1) * 64;
    const int col = lane & 15, quad = lane >> 4;
    const short* Ab = Act + (long)b * M * K;

    float4_ acc[4][4];
    #pragma unroll
    for (int i = 0; i < 4; ++i)
        #pragma unroll
        for (int j = 0; j < 4; ++j)
            acc[i][j] = (float4_){0.f, 0.f, 0.f, 0.f};

    const int arow = t >> 2, aseg = t & 3;
    for (int k0 = 0; k0 < K; k0 += 32) {
        __syncthreads();
        #pragma unroll
        for (int hh = 0; hh < 2; ++hh) {
            int row = arow + hh * 64;
            int gm = m0 + row;
            float4 av = make_float4(0.f, 0.f, 0.f, 0.f);
            if (gm < M) av = *(const float4*)(Ab + (long)gm * K + k0 + aseg * 8);
            *(float4*)(As + row * 40 + aseg * 8) = av;
            float4 bv = *(const float4*)(Wb + (long)(n0 + row) * K + k0 + aseg * 8);
            *(float4*)(Bs + row * 40 + aseg * 8) = bv;
        }
        __syncthreads();
        short8 af[4], bf[4];
        #pragma unroll
        for (int i = 0; i < 4; ++i)
            af[i] = *(const short8*)(As + (wm + i * 16 + col) * 40 + quad * 8);
        #pragma unroll
        for (int j = 0; j < 4; ++j)
            bf[j] = *(const short8*)(Bs + (wn + j * 16 + col) * 40 + quad * 8);
        #pragma unroll
        for (int i = 0; i < 4; ++i)
            #pragma unroll
            for (int j = 0; j < 4; ++j)
                acc[i][j] = __builtin_amdgcn_mfma_f32_16x16x32_bf16(af[i], bf[j], acc[i][j], 0, 0, 0);
    }

    float s1 = 0.f, s2s = 0.f;
    #pragma unroll
    for (int i = 0; i < 4; ++i) {
        int pbase = m0 + wm + i * 16 + quad * 4;
        #pragma unroll
        for (int j = 0; j < 4; ++j) {
            int oc = n0 + wn + j * 16 + col;
            if (EPI == 0) {
                float cb = bias[oc];
                #pragma unroll
                for (int r = 0; r < 4; ++r) {
                    int p = pbase + r;
                    if (p < M) outh[((long)b * M + p) * N + oc] = f2bf(acc[i][j][r] + cb);
                }
            } else if (EPI == 1) {
                float sc = g[oc] * rsqrtf(vv[oc] + EPS_);
                float sh = bb[oc] - mm[oc] * sc;
                float cb = bias[oc];
                #pragma unroll
                for (int r = 0; r < 4; ++r) {
                    int p = pbase + r;
                    if (p < M) outh[((long)b * M + p) * N + oc] =
                        f2bf(gelu_f((acc[i][j][r] + cb) * sc + sh));
                }
            } else if (EPI == 2) {
                float cb = bias[oc];
                if (pbase < M) {
                    #pragma unroll
                    for (int r = 0; r < 4; ++r) {
                        long jj = ((long)b * M + pbase + r) * 256 + oc;
                        float val = acc[i][j][r] + cb + res[jj];
                        outf[jj] = val;
                        s1 += val; s2s += val * val;
                    }
                }
            } else {
                float sc = g[oc] * rsqrtf(vv[oc] + EPS_);
                float sh = bb[oc] - mm[oc] * sc;
                float cb = bias[oc];
                if (pbase < M) {
                    long base = ((long)b * N + oc) * M + pbase;
                    float4 rv = *(const float4*)(res + base);
                    float4 y;
                    y.x = (acc[i][j][0] + cb) * sc + sh + rv.x;
                    y.y = (acc[i][j][1] + cb) * sc + sh + rv.y;
                    y.z = (acc[i][j][2] + cb) * sc + sh + rv.z;
                    y.w = (acc[i][j][3] + cb) * sc + sh + rv.w;
                    *(float4*)(outf + base) = y;
                }
            }
        }
    }
    if (EPI == 2) {
        #pragma unroll
        for (int o = 32; o > 0; o >>= 1) {
            s1 += __shfl_down(s1, o);
            s2s += __shfl_down(s2s, o);
        }
        if (lane == 0) {
            long slot = (((long)blockIdx.z * gridDim.y + blockIdx.y) * gridDim.x + blockIdx.x) * 4 + w;
            opart[slot * 2]     = s1;
            opart[slot * 2 + 1] = s2s;
        }
    }
}

// ---- MFMA flash attention v2: S^T trick ----
// Computes S^T = K·Q^T so each lane holds (4 consecutive keys, 1 query):
// pos_b loads become float4, P writes become ds_write_b64 into Ps[q][key]
// (exactly the A-layout PV needs). 64-key chunks; no max-subtraction
// (scores bounded); per-wave-private Ps rows -> no barrier in the k-loop.
__global__ __launch_bounds__(256) void attn_kernel(const short* __restrict__ q,
                                                   const short* __restrict__ k,
                                                   const short* __restrict__ v,
                                                   const float* __restrict__ pos_b,
                                                   short* __restrict__ out) {
    __shared__ short Ks[224 * 40];   // [key][d], rows >=196 zero
    __shared__ short Vt[32 * 248];   // [d][key], cols >=196 zero
    __shared__ short Ps[128 * 72];   // [q][key-in-chunk(64)], per-wave rows
    __shared__ float Ls[128];        // 1/rowsum per q
    const int qt0 = blockIdx.x * 128;
    const int h = blockIdx.y;
    const int b = blockIdx.z;
    const int t = threadIdx.x;
    const short8 z8 = {0, 0, 0, 0, 0, 0, 0, 0};
    // stage K (224 rows x 4 segs of 16B)
    for (int e = t; e < 896; e += 256) {
        int row = e >> 2, seg = e & 3;
        short8 v8 = (row < NKPIX)
            ? *(const short8*)(k + ((long)(b * NKPIX + row)) * 256 + h * 32 + seg * 8) : z8;
        *(short8*)(Ks + row * 40 + seg * 8) = v8;
    }
    // stage V transposed: vectorized global loads, b16 scatter into LDS
    for (int e = t; e < 784; e += 256) {
        int key = e >> 2, seg = e & 3;
        short8 tv = *(const short8*)(v + ((long)(b * NKPIX + key)) * 256 + h * 32 + seg * 8);
        #pragma unroll
        for (int j = 0; j < 8; ++j) Vt[(seg * 8 + j) * 248 + key] = tv[j];
    }
    // zero Vt pad cols 196..247
    for (int e = t; e < 32 * 52; e += 256) {
        Vt[(e / 52) * 248 + 196 + (e % 52)] = 0;
    }
    __syncthreads();

    const int w = t >> 6, lane = t & 63;
    const int col = lane & 15, quad = lane >> 4;
    const float scale = 0.17677669529663689f;
    const float4_ z4 = {0.f, 0.f, 0.f, 0.f};

    // Q fragments direct from global (B-operand rows = this wave's queries)
    short8 bq_[2];
    int qrow[2]; bool qvalid[2];
    #pragma unroll
    for (int i = 0; i < 2; ++i) {
        qrow[i] = qt0 + w * 32 + i * 16 + col;
        qvalid[i] = qrow[i] < NPIX;
        int qe = qvalid[i] ? qrow[i] : 0;
        bq_[i] = *(const short8*)(q + ((long)(b * NPIX + qe)) * 256 + h * 32 + quad * 8);
    }

    float4_ accO[2][2];
    #pragma unroll
    for (int i = 0; i < 2; ++i)
        #pragma unroll
        for (int nt = 0; nt < 2; ++nt) accO[i][nt] = z4;
    float lsum[2] = {0.f, 0.f};

    const int prow0 = w * 32;
    #pragma unroll
    for (int kc = 0; kc < 4; ++kc) {
        const int base = kc * 64;
        const int ntn = (kc == 3) ? 2 : 4;
        // ---- S^T pass: A = K-tile, B = Q-frag ----
        for (int nt = 0; nt < ntn; ++nt) {
            short8 afk = *(const short8*)(Ks + (base + nt * 16 + col) * 40 + quad * 8);
            int keybase = base + nt * 16 + quad * 4;
            bool kval = keybase < NKPIX;
            #pragma unroll
            for (int i = 0; i < 2; ++i) {
                float4_ s4 = __builtin_amdgcn_mfma_f32_16x16x32_bf16(afk, bq_[i], z4, 0, 0, 0);
                float4 pv = make_float4(0.f, 0.f, 0.f, 0.f);
                bool valid = kval && qvalid[i];
                if (valid)
                    pv = *(const float4*)(pos_b + ((long)h * NPIX + qrow[i]) * NKPIX + keybase);
                float p0 = valid ? __expf(s4[0] * scale + pv.x) : 0.f;
                float p1 = valid ? __expf(s4[1] * scale + pv.y) : 0.f;
                float p2 = valid ? __expf(s4[2] * scale + pv.z) : 0.f;
                float p3 = valid ? __expf(s4[3] * scale + pv.w) : 0.f;
                lsum[i] += p0 + p1 + p2 + p3;
                short4_ pk = {f2bf(p0), f2bf(p1), f2bf(p2), f2bf(p3)};
                *(short4_*)(Ps + (prow0 + i * 16 + col) * 72 + nt * 16 + quad * 4) = pk;
            }
        }
        // ---- PV pass (same-wave LDS rows; lgkmcnt orders it) ----
        const int ksn = (kc == 3) ? 1 : 2;
        for (int ks = 0; ks < ksn; ++ks) {
            #pragma unroll
            for (int i = 0; i < 2; ++i) {
                short8 afp = *(const short8*)(Ps + (prow0 + i * 16 + col) * 72 + ks * 32 + quad * 8);
                #pragma unroll
                for (int nt = 0; nt < 2; ++nt) {
                    short8 bfv = *(const short8*)(Vt + (nt * 16 + col) * 248 + base + ks * 32 + quad * 8);
                    accO[i][nt] = __builtin_amdgcn_mfma_f32_16x16x32_bf16(afp, bfv, accO[i][nt], 0, 0, 0);
                }
            }
        }
    }
    // rowsum reduce across quads (lanes sharing col differ in bits 4..5)
    #pragma unroll
    for (int i = 0; i < 2; ++i) {
        float s = lsum[i];
        s += __shfl_xor(s, 16);
        s += __shfl_xor(s, 32);
        if (quad == 0) Ls[prow0 + i * 16 + col] = 1.f / s;
    }
    // epilogue: O in C-layout (m = q = quad*4+r, n = d = nt*16+col)
    #pragma unroll
    for (int i = 0; i < 2; ++i) {
        int qb0 = qt0 + prow0 + i * 16 + quad * 4;
        #pragma unroll
        for (int r = 0; r < 4; ++r) {
            int qq = qb0 + r;
            if (qq >= NPIX) continue;
            float rinv = Ls[prow0 + i * 16 + quad * 4 + r];
            #pragma unroll
            for (int nt = 0; nt < 2; ++nt)
                out[((long)(b * NPIX + qq)) * 256 + h * 32 + nt * 16 + col] =
                    f2bf(accO[i][nt][r] * rinv);
        }
    }
}

// ---- dwconv3x3 + BN2 + GELU, 8 channels/thread via short8 ----
__global__ __launch_bounds__(256) void dwgelu_kernel(
    const short* __restrict__ t2, const float* __restrict__ wt,
    const float* __restrict__ sc2, const float* __restrict__ sh2,
    short* __restrict__ t3) {
    int idx = blockIdx.x * 256 + threadIdx.x;  // B*NPIX*128 = 3,211,264
    int cm8 = idx & 127;
    int rest = idx >> 7;
    int p = rest % NPIX;
    int b = rest / NPIX;
    int py = p / W_, px = p % W_;
    int cm0 = cm8 * 8;
    const short* tb = t2 + ((long)b * NPIX) * CM + cm0;
    float acc[8];
    #pragma unroll
    for (int r = 0; r < 8; ++r) acc[r] = 0.f;
    #pragma unroll
    for (int dy = -1; dy <= 1; ++dy) {
        int yy = py + dy;
        if (yy < 0 || yy >= H_) continue;
        #pragma unroll
        for (int dx = -1; dx <= 1; ++dx) {
            int xc = px + dx;
            if (xc < 0 || xc >= W_) continue;
            int tap = (dy + 1) * 3 + (dx + 1);
            short8 tv = *(const short8*)(tb + (long)(yy * W_ + xc) * CM);
            float4 w0 = *(const float4*)(wt + tap * 1024 + cm0);
            float4 w1 = *(const float4*)(wt + tap * 1024 + cm0 + 4);
            acc[0] += bf2f(tv[0]) * w0.x;
            acc[1] += bf2f(tv[1]) * w0.y;
            acc[2] += bf2f(tv[2]) * w0.z;
            acc[3] += bf2f(tv[3]) * w0.w;
            acc[4] += bf2f(tv[4]) * w1.x;
            acc[5] += bf2f(tv[5]) * w1.y;
            acc[6] += bf2f(tv[6]) * w1.z;
            acc[7] += bf2f(tv[7]) * w1.w;
        }
    }
    float4 sa = *(const float4*)(sc2 + cm0);
    float4 sb = *(const float4*)(sc2 + cm0 + 4);
    float4 ha = *(const float4*)(sh2 + cm0);
    float4 hb = *(const float4*)(sh2 + cm0 + 4);
    short8 ov;
    ov[0] = f2bf(gelu_f(acc[0] * sa.x + ha.x));
    ov[1] = f2bf(gelu_f(acc[1] * sa.y + ha.y));
    ov[2] = f2bf(gelu_f(acc[2] * sa.z + ha.z));
    ov[3] = f2bf(gelu_f(acc[3] * sa.w + ha.w));
    ov[4] = f2bf(gelu_f(acc[4] * sb.x + hb.x));
    ov[5] = f2bf(gelu_f(acc[5] * sb.y + hb.y));
    ov[6] = f2bf(gelu_f(acc[6] * sb.z + hb.z));
    ov[7] = f2bf(gelu_f(acc[7] * sb.w + hb.w));
    *(short8*)(t3 + ((long)b * NPIX + p) * CM + cm0) = ov;
}

extern "C" void kernel_launch(void* const* d_in, const int* in_sizes, int n_in,
                              void* d_out, int out_size, void* d_ws, size_t ws_size,
                              hipStream_t stream) {
    const float* x     = (const float*)d_in[0];
    const float* lpu_w = (const float*)d_in[1];
    const float* lpu_b = (const float*)d_in[2];
    const float* dw_w  = (const float*)d_in[3];
    const float* dw_b  = (const float*)d_in[4];
    const float* wq    = (const float*)d_in[5];
    const float* bq    = (const float*)d_in[6];
    const float* wk    = (const float*)d_in[7];
    const float* bk    = (const float*)d_in[8];
    const float* wv    = (const float*)d_in[9];
    const float* bv    = (const float*)d_in[10];
    const float* wo    = (const float*)d_in[11];
    const float* bo    = (const float*)d_in[12];
    const float* posb  = (const float*)d_in[13];
    const float* c1_w  = (const float*)d_in[14];
    const float* c1_b  = (const float*)d_in[15];
    const float* bn1_g = (const float*)d_in[16];
    const float* bn1_b = (const float*)d_in[17];
    const float* bn1_m = (const float*)d_in[18];
    const float* bn1_v = (const float*)d_in[19];
    const float* dw2_w = (const float*)d_in[20];
    const float* dw2_b = (const float*)d_in[21];
    const float* bn2_g = (const float*)d_in[22];
    const float* bn2_b = (const float*)d_in[23];
    const float* bn2_m = (const float*)d_in[24];
    const float* bn2_v = (const float*)d_in[25];
    const float* c2_w  = (const float*)d_in[26];
    const float* c2_b  = (const float*)d_in[27];
    const float* bn3_g = (const float*)d_in[28];
    const float* bn3_b = (const float*)d_in[29];
    const float* bn3_m = (const float*)d_in[30];
    const float* bn3_v = (const float*)d_in[31];

    const long n1  = (long)B_ * C_ * NPIX;    // 6,422,528
    const long nkv = (long)B_ * C_ * NKPIX;   // 1,605,632
    const long nm  = (long)B_ * CM * NPIX;    // 25,690,112
    const int  nblk1 = (int)(n1 / 256);       // 25088 lpu blocks (784 per sample)

    char* base = (char*)d_ws;
    float* x1   = (float*)base; base += n1 * 4;
    float* x2c  = (float*)base; base += n1 * 4;
    short* x1n  = (short*)base; base += n1 * 2;
    short* qb   = (short*)base; base += n1 * 2;
    short* tmpb = (short*)base; base += n1 * 2;
    short* t1n  = (short*)base; base += n1 * 2;
    short* kvb  = (short*)base; base += nkv * 2;
    short* kb   = (short*)base; base += nkv * 2;
    short* vb   = (short*)base; base += nkv * 2;
    short* t2   = (short*)base; base += nm * 2;
    short* t3   = (short*)base; base += nm * 2;
    short* wbf  = (short*)base; base += 786432L * 2;
    float* stats = (float*)base; base += 128 * 4;
    float* dwt   = (float*)base; base += 9216 * 4;   // [9][1024]
    float* dsc   = (float*)base; base += 1024 * 4;
    float* dsh   = (float*)base; base += 1024 * 4;
    float* part1 = (float*)base; base += (long)nblk1 * 2 * 4;
    float* part2 = (float*)base;
    float* outp = (float*)d_out;

    wconv_kernel<<<3072, 256, 0, stream>>>(wq, wk, wv, wo, c1_w, c2_w, wbf);
    dwprep_kernel<<<4, 256, 0, stream>>>(dw2_w, dw2_b, bn2_g, bn2_b, bn2_m, bn2_v,
                                         dwt, dsc, dsh);
    lpu_kernel<<<nblk1, 256, 0, stream>>>(x, lpu_w, lpu_b, x1, part1);
    lnreduce_kernel<<<B_, 256, 0, stream>>>(part1, nblk1 / B_, stats);
    kvconv_kernel<<<(int)((nkv + 255) / 256), 256, 0, stream>>>(x1, dw_w, dw_b, kvb);
    tln_kernel<<<dim3(25, 8, B_), 256, 0, stream>>>(x1, stats, x1n);
    // q/k/v projections
    mfma_gemm<0><<<dim3(7, 2, B_), 256, 0, stream>>>(
        x1n, wbf, NPIX, 256, 256, bq, nullptr, nullptr, nullptr, nullptr,
        nullptr, nullptr, qb, nullptr);
    mfma_gemm<0><<<dim3(2, 2, B_), 256, 0, stream>>>(
        kvb, wbf + 65536, NKPIX, 256, 256, bk, nullptr, nullptr, nullptr, nullptr,
        nullptr, nullptr, kb, nullptr);
    mfma_gemm<0><<<dim3(2, 2, B_), 256, 0, stream>>>(
        kvb, wbf + 131072, NKPIX, 256, 256, bv, nullptr, nullptr, nullptr, nullptr,
        nullptr, nullptr, vb, nullptr);
    attn_kernel<<<dim3(7, 8, B_), 256, 0, stream>>>(qb, kb, vb, posb, tmpb);
    // wo + flat residual + per-wave LN2 partials (grid 7x2x32 -> 56 slots per b)
    mfma_gemm<2><<<dim3(7, 2, B_), 256, 0, stream>>>(
        tmpb, wbf + 196608, NPIX, 256, 256, bo, nullptr, nullptr, nullptr, nullptr,
        x1, part2, nullptr, x2c);
    lnreduce_kernel<<<B_, 256, 0, stream>>>(part2, 56, stats + 64);
    tln_kernel<<<dim3(25, 8, B_), 256, 0, stream>>>(x2c, stats + 64, t1n);
    // conv1 1x1 + BN1 + GELU
    mfma_gemm<1><<<dim3(7, 8, B_), 256, 0, stream>>>(
        t1n, wbf + 262144, NPIX, CM, 256, c1_b, bn1_g, bn1_b, bn1_m, bn1_v,
        nullptr, nullptr, t2, nullptr);
    dwgelu_kernel<<<(int)(B_ * NPIX * 128 / 256), 256, 0, stream>>>(t2, dwt, dsc, dsh, t3);
    // conv2 1x1 + BN3 + residual -> d_out (channel-major)
    mfma_gemm<3><<<dim3(7, 2, B_), 256, 0, stream>>>(
        t3, wbf + 524288, NPIX, 256, CM, c2_b, bn3_g, bn3_b, bn3_m, bn3_v,
        x2c, nullptr, nullptr, outp);
}